// Round 12
// baseline (93.613 us; speedup 1.0000x reference)
//
#include <hip/hip_runtime.h>
#include <hip/hip_bf16.h>

#define NBOX  380
#define NLOCS 85
#define NINST 340   // B(4) * NLOCS(85)

// box index -> location index (from _recon_indices structure)
__device__ __forceinline__ int loc_of_box(int n) {
    if (n < 256) return n >> 2;               // fm=8, 4 boxes/loc
    if (n < 352) return 64 + (n - 256) / 6;   // fm=4, 6 boxes/loc
    if (n < 376) return 80 + (n - 352) / 6;   // fm=2, 6 boxes/loc
    return 84;                                // fm=1, 4 boxes/loc
}

__device__ __forceinline__ float f4e(const float4& v, int kk) {
    return (kk == 0) ? v.x : (kk == 1) ? v.y : (kk == 2) ? v.z : v.w;
}

// Per-batch softmax over depths + per-box affine params + rect + compaction.
// 512 threads. Uses sm[0..896).
__device__ void box_params_dev(int b, const float* __restrict__ zwhere,
    const int* __restrict__ zpresent, const float* __restrict__ zdepth,
    float* wgt, float* sxs, float* oxs, float* sys, float* oys,
    int* binst, int* rect, int* cidx, int* cnt, float* sm)
{
    float* sd  = sm;         // 384 (380 used)
    float* red = sm + 384;   // 512
    const int tid = threadIdx.x;

    if (tid < NBOX) {
        int loc = loc_of_box(tid);
        sd[tid] = (zpresent[b * NBOX + tid] == 1) ? zdepth[b * NLOCS + loc] : -1000.0f;
    }
    __syncthreads();

    float m = (tid < NBOX) ? sd[tid] : -1e30f;
    red[tid] = m; __syncthreads();
    for (int s = 256; s > 0; s >>= 1) {
        if (tid < s) red[tid] = fmaxf(red[tid], red[tid + s]);
        __syncthreads();
    }
    m = red[0]; __syncthreads();

    float sum = (tid < NBOX) ? expf(sd[tid] - m) : 0.f;
    red[tid] = sum; __syncthreads();
    for (int s = 256; s > 0; s >>= 1) {
        if (tid < s) red[tid] += red[tid + s];
        __syncthreads();
    }
    float inv = 1.0f / red[0];
    __syncthreads();

    if (tid < NBOX) {
        int g = b * NBOX + tid;
        float wv = expf(sd[tid] - m) * inv;   // exp(-1000-m) underflows to exactly 0
        wgt[g] = wv;
        float cx = zwhere[g * 4 + 0], cy = zwhere[g * 4 + 1];
        float w  = zwhere[g * 4 + 2], h  = zwhere[g * 4 + 3];
        float isx = 1.0f / fmaxf(w, 1e-5f);
        float isy = 1.0f / fmaxf(h, 1e-5f);
        float sxv = isx * (63.0f / 127.0f);
        float oxv = 31.5f * (1.0f - 2.0f * cx * isx);
        float syv = isy * (63.0f / 127.0f);
        float oyv = 31.5f * (1.0f - 2.0f * cy * isy);
        sxs[g] = sxv; oxs[g] = oxv; sys[g] = syv; oys[g] = oyv;
        binst[g] = b * NLOCS + loc_of_box(tid);
        int wlo = min(127, max(0, (int)floorf((-1.0f - oxv) / sxv)));
        int whi = max(0, min(127, (int)ceilf((64.0f - oxv) / sxv)));
        int hlo = min(127, max(0, (int)floorf((-1.0f - oyv) / syv)));
        int hhi = max(0, min(127, (int)ceilf((64.0f - oyv) / syv)));
        rect[g] = wlo | (whi << 8) | (hlo << 16) | (hhi << 24);
        sd[tid] = wv;   // presence flag for compaction
    }
    __syncthreads();

    if (tid < 64) {   // wave 0: deterministic ascending compaction
        int base = 0;
        for (int c = 0; c < 6; ++c) {
            int n = c * 64 + tid;
            bool p = (n < NBOX) && (sd[n] > 0.0f);
            unsigned long long mask = __ballot(p);
            int pos = __popcll(mask & ((1ull << tid) - 1ull));
            if (p) cidx[b * NBOX + base + pos] = n;
            base += __popcll(mask);
        }
        if (tid == 0) cnt[b] = base;
    }
}

// Decoder chain: ONE (loc, batch-PAIR, row-half) per block. 512 threads.
// The 4 batches share weights -> pairing 2 batches per block doubles the
// FMAs fed by every weight load (and per-thread ILP) at ZERO extra L2 weight
// traffic and the same 340-block grid as SPLIT=1 (R9..R11 traffic model).
// out[(2i+di, 2j+dj)][co] = act( b[co] + sum_k x[i,j][k] * W[1-di][1-dj][k][co] )
// LDS per batch (floats, base q*7680): aL0 +0 (512) | aL1 +512 (1024) |
//   aL2 +1536 (2048) | aL4 +0 overlay (2176) | s_x/aL3 +3584 (4096, s_x dead
//   after L0). Total 15360 floats = 61,440 B -> 2 blocks/CU.
// Rules honored: all register arrays static-indexed (FULL unrolls, R8 lesson);
// single weight stream pair per thread (R11 L1 traffic lesson).
__global__ __launch_bounds__(512, 2) void decode_fused_k(
    const float* __restrict__ z_what,
    const float* __restrict__ W0, const float* __restrict__ B0,
    const float* __restrict__ W1, const float* __restrict__ B1,
    const float* __restrict__ W2, const float* __restrict__ B2,
    const float* __restrict__ W3, const float* __restrict__ B3,
    const float* __restrict__ W4, const float* __restrict__ B4,
    const float* __restrict__ W5, const float* __restrict__ B5,
    const float* __restrict__ z_where, const int* __restrict__ z_present,
    const float* __restrict__ z_depth,
    float* __restrict__ wgt, float* __restrict__ sxs, float* __restrict__ oxs,
    float* __restrict__ sys, float* __restrict__ oys, int* __restrict__ binst,
    int* __restrict__ rect, int* __restrict__ cidx, int* __restrict__ cnt,
    float* __restrict__ dec)
{
    __shared__ __align__(16) float sm[15360];   // 61,440 B

    const int bid = blockIdx.x;
    if (bid >= NINST) {   // 4 trailing blocks: box params
        box_params_dev(bid - NINST, z_where, z_present, z_depth,
                       wgt, sxs, oxs, sys, oys, binst, rect, cidx, cnt, sm);
        return;
    }
    const int loc = bid % 85;
    const int r2  = bid / 85;              // 0..3
    const int bp  = r2 & 1, s = r2 >> 1;   // batch-pair, row-half
    const int inst0 = (2 * bp + 0) * 85 + loc;
    const int inst1 = (2 * bp + 1) * 85 + loc;

    const int tid = threadIdx.x;

    if (tid < 128) {   // s_x for both batches at +3584
        int q = tid >> 6, l = tid & 63;
        sm[q * 7680 + 3584 + l] = z_what[(q ? inst1 : inst0) * 64 + l];
    }
    __syncthreads();

    // ---- L0: K=64 -> 256ch, row s, cols 0..1. thread=(j0, c0), 2 batches.
    {
        const int c0 = tid & 255, j0 = tid >> 8;
        const int ft = 3 - (2 * s + j0);
        const float* wp = W0 + (size_t)ft * 64 * 256 + c0;
        const float* x0 = sm + 3584;
        const float* x1 = sm + 7680 + 3584;
        float a0 = 0.f, a1 = 0.f;
        #pragma unroll 8
        for (int k = 0; k < 64; ++k) {
            float w = wp[k * 256];
            a0 = fmaf(x0[k], w, a0);
            a1 = fmaf(x1[k], w, a1);
        }
        float bb = B0[c0];
        sm[j0 * 256 + c0]        = fmaxf(a0 + bb, 0.f);
        sm[7680 + j0 * 256 + c0] = fmaxf(a1 + bb, 0.f);
    }
    __syncthreads();

    // ---- L1: K=256 -> 128ch, rows 2s..2s+1, cols 0..3. thread=(tap, c1):
    // 1 weight stream feeds 2 j x 2 batches = 4 FMAs.
    {
        const int c1 = tid & 127, t = tid >> 7;
        const int di = t >> 1, dj = t & 1, ft = 3 - t;
        const float* wp = W1 + (size_t)ft * 256 * 128 + c1;
        float aA0 = 0.f, aA1 = 0.f, aB0 = 0.f, aB1 = 0.f;   // [batch][j]
        #pragma unroll 4
        for (int kq = 0; kq < 64; ++kq) {
            int k0 = kq * 4;
            float4 vA0 = *(const float4*)&sm[0 * 256 + k0];
            float4 vA1 = *(const float4*)&sm[1 * 256 + k0];
            float4 vB0 = *(const float4*)&sm[7680 + 0 * 256 + k0];
            float4 vB1 = *(const float4*)&sm[7680 + 1 * 256 + k0];
            #pragma unroll
            for (int kk = 0; kk < 4; ++kk) {
                float w = wp[(k0 + kk) * 128];
                aA0 = fmaf(f4e(vA0, kk), w, aA0);
                aA1 = fmaf(f4e(vA1, kk), w, aA1);
                aB0 = fmaf(f4e(vB0, kk), w, aB0);
                aB1 = fmaf(f4e(vB1, kk), w, aB1);
            }
        }
        float bb = B1[c1];
        int o0 = (di * 4 + 0 + dj) * 128 + c1;   // j=0 -> col dj
        int o1 = (di * 4 + 2 + dj) * 128 + c1;   // j=1 -> col 2+dj
        sm[512 + o0]        = fmaxf(aA0 + bb, 0.f);
        sm[512 + o1]        = fmaxf(aA1 + bb, 0.f);
        sm[7680 + 512 + o0] = fmaxf(aB0 + bb, 0.f);
        sm[7680 + 512 + o1] = fmaxf(aB1 + bb, 0.f);
    }
    __syncthreads();

    // ---- L2: K=128 -> 64ch, rows 4s..4s+3, cols 0..7. thread=(x2, c2):
    // 2 weight streams (di pair), each feeds 2 il x 2 batches = 4 FMAs.
    {
        const int c2 = tid & 63, x2 = tid >> 6;   // 0..7
        const int j = x2 >> 1, dj = x2 & 1;
        const float* wA = W2 + (size_t)(3 - dj) * 128 * 64 + c2;
        const float* wB = W2 + (size_t)(1 - dj) * 128 * 64 + c2;
        float acc[2][2][2];   // [q][il][di]
        #pragma unroll
        for (int q = 0; q < 2; ++q)
            #pragma unroll
            for (int il = 0; il < 2; ++il) { acc[q][il][0] = 0.f; acc[q][il][1] = 0.f; }
        #pragma unroll 2
        for (int kq = 0; kq < 32; ++kq) {
            int k0 = kq * 4;
            float4 xr[2][2];
            #pragma unroll
            for (int q = 0; q < 2; ++q)
                #pragma unroll
                for (int il = 0; il < 2; ++il)
                    xr[q][il] = *(const float4*)&sm[q * 7680 + 512 + (il * 4 + j) * 128 + k0];
            #pragma unroll
            for (int kk = 0; kk < 4; ++kk) {
                float wa = wA[(k0 + kk) * 64], wb = wB[(k0 + kk) * 64];
                #pragma unroll
                for (int q = 0; q < 2; ++q)
                    #pragma unroll
                    for (int il = 0; il < 2; ++il) {
                        float e = f4e(xr[q][il], kk);
                        acc[q][il][0] = fmaf(e, wa, acc[q][il][0]);
                        acc[q][il][1] = fmaf(e, wb, acc[q][il][1]);
                    }
            }
        }
        float bb = B2[c2];
        #pragma unroll
        for (int q = 0; q < 2; ++q)
            #pragma unroll
            for (int il = 0; il < 2; ++il)
                #pragma unroll
                for (int di = 0; di < 2; ++di)
                    sm[q * 7680 + 1536 + ((2 * il + di) * 8 + x2) * 64 + c2] =
                        fmaxf(acc[q][il][di] + bb, 0.f);
    }
    __syncthreads();

    // ---- L3: K=64 -> 32ch, rows 8s..8s+7, cols 0..15. thread=(x3, c3):
    // 2 weight streams, each feeds 4 il x 2 batches = 8 FMAs.
    {
        const int c3 = tid & 31, x3 = tid >> 5;   // 0..15
        const int j = x3 >> 1, dj = x3 & 1;
        const float* wA = W3 + (size_t)(3 - dj) * 64 * 32 + c3;
        const float* wB = W3 + (size_t)(1 - dj) * 64 * 32 + c3;
        float acc[2][4][2];   // [q][il][di]
        #pragma unroll
        for (int q = 0; q < 2; ++q)
            #pragma unroll
            for (int il = 0; il < 4; ++il) { acc[q][il][0] = 0.f; acc[q][il][1] = 0.f; }
        #pragma unroll 2
        for (int kq = 0; kq < 16; ++kq) {
            int k0 = kq * 4;
            float4 xr[2][4];
            #pragma unroll
            for (int q = 0; q < 2; ++q)
                #pragma unroll
                for (int il = 0; il < 4; ++il)
                    xr[q][il] = *(const float4*)&sm[q * 7680 + 1536 + (il * 8 + j) * 64 + k0];
            #pragma unroll
            for (int kk = 0; kk < 4; ++kk) {
                float wa = wA[(k0 + kk) * 32], wb = wB[(k0 + kk) * 32];
                #pragma unroll
                for (int q = 0; q < 2; ++q)
                    #pragma unroll
                    for (int il = 0; il < 4; ++il) {
                        float e = f4e(xr[q][il], kk);
                        acc[q][il][0] = fmaf(e, wa, acc[q][il][0]);
                        acc[q][il][1] = fmaf(e, wb, acc[q][il][1]);
                    }
            }
        }
        float bb = B3[c3];
        #pragma unroll
        for (int q = 0; q < 2; ++q)
            #pragma unroll
            for (int il = 0; il < 4; ++il)
                #pragma unroll
                for (int di = 0; di < 2; ++di)
                    sm[q * 7680 + 3584 + ((2 * il + di) * 16 + x3) * 32 + c3] =
                        fmaxf(acc[q][il][di] + bb, 0.f);
    }
    __syncthreads();

    // ---- L4 + L5 fused, 4 chunks of 2 L3-rows -> 4 L4-rows -> 8 final rows.
    const float b50 = B5[0], b51 = B5[1], b52 = B5[2];
    // L5 tap regs per thread: out rows g (di=g&1), col x5 (dj=x5&1).
    const int x5 = tid & 63, g5 = tid >> 6;
    const int dj5 = x5 & 1, di5 = g5 & 1;
    const int ft5 = 3 - (2 * di5 + dj5);
    float w5r[16][3];
    #pragma unroll
    for (int k = 0; k < 16; ++k) {
        w5r[k][0] = W5[(ft5 * 16 + k) * 3 + 0];
        w5r[k][1] = W5[(ft5 * 16 + k) * 3 + 1];
        w5r[k][2] = W5[(ft5 * 16 + k) * 3 + 2];
    }

    for (int c = 0; c < 4; ++c) {
        {   // L4: K=32 -> 16ch, input L3 local rows 2c..2c+1, out chunk rows 0..3.
            const int c4 = tid & 15, x4 = tid >> 4;   // 0..31
            const int j = x4 >> 1, dj = x4 & 1;
            const float* wA = W4 + (size_t)(3 - dj) * 32 * 16 + c4;
            const float* wB = W4 + (size_t)(1 - dj) * 32 * 16 + c4;
            float acc[2][2][2];   // [q][il][di]
            #pragma unroll
            for (int q = 0; q < 2; ++q)
                #pragma unroll
                for (int il = 0; il < 2; ++il) { acc[q][il][0] = 0.f; acc[q][il][1] = 0.f; }
            #pragma unroll
            for (int kq = 0; kq < 8; ++kq) {
                int k0 = kq * 4;
                float4 xr[2][2];
                #pragma unroll
                for (int q = 0; q < 2; ++q)
                    #pragma unroll
                    for (int il = 0; il < 2; ++il)
                        xr[q][il] = *(const float4*)
                            &sm[q * 7680 + 3584 + ((2 * c + il) * 16 + j) * 32 + k0];
                #pragma unroll
                for (int kk = 0; kk < 4; ++kk) {
                    float wa = wA[(k0 + kk) * 16], wb = wB[(k0 + kk) * 16];
                    #pragma unroll
                    for (int q = 0; q < 2; ++q)
                        #pragma unroll
                        for (int il = 0; il < 2; ++il) {
                            float e = f4e(xr[q][il], kk);
                            acc[q][il][0] = fmaf(e, wa, acc[q][il][0]);
                            acc[q][il][1] = fmaf(e, wb, acc[q][il][1]);
                        }
                }
            }
            float bb = B4[c4];
            #pragma unroll
            for (int q = 0; q < 2; ++q)
                #pragma unroll
                for (int il = 0; il < 2; ++il)
                    #pragma unroll
                    for (int di = 0; di < 2; ++di)
                        sm[q * 7680 + ((2 * il + di) * 32 + x4) * 17 + c4] =
                            fmaxf(acc[q][il][di] + bb, 0.f);
        }
        __syncthreads();
        {   // L5: K=16 -> 3ch sigmoid; out rows 8c+g5 (global 32s+8c+g5), col x5.
            const int jl = x5 >> 1;
            const int lr = g5 >> 1;   // L4 chunk-local input row 0..3
            float a[2][3];
            #pragma unroll
            for (int q = 0; q < 2; ++q) { a[q][0] = b50; a[q][1] = b51; a[q][2] = b52; }
            #pragma unroll
            for (int k = 0; k < 16; ++k) {
                #pragma unroll
                for (int q = 0; q < 2; ++q) {
                    float xv = sm[q * 7680 + (lr * 32 + jl) * 17 + k];
                    a[q][0] = fmaf(xv, w5r[k][0], a[q][0]);
                    a[q][1] = fmaf(xv, w5r[k][1], a[q][1]);
                    a[q][2] = fmaf(xv, w5r[k][2], a[q][2]);
                }
            }
            int row = 32 * s + 8 * c + g5;
            #pragma unroll
            for (int q = 0; q < 2; ++q) {
                float v0 = 1.0f / (1.0f + expf(-a[q][0]));
                float v1 = 1.0f / (1.0f + expf(-a[q][1]));
                float v2 = 1.0f / (1.0f + expf(-a[q][2]));
                float* dp = dec + (size_t)(q ? inst1 : inst0) * 12288
                          + (size_t)(row * 64 + x5) * 3;
                dp[0] = v0; dp[1] = v1; dp[2] = v2;
            }
        }
        __syncthreads();
    }
}

// Fused STN bilinear sample + weighted composite + in-block reduce.
// grid 512 = (b, 16x8 px tile); 1024 threads = 8 box-splits x 128 px.
__global__ __launch_bounds__(1024) void composite_k(
    const float* __restrict__ dec, const float* __restrict__ wgt,
    const float* __restrict__ sxs, const float* __restrict__ oxs,
    const float* __restrict__ sys, const float* __restrict__ oys,
    const int* __restrict__ binst, const int* __restrict__ rect,
    const int* __restrict__ cidx, const int* __restrict__ cnt,
    float* __restrict__ out)
{
    __shared__ float pls[8][128][3];   // 12 KB

    int b = blockIdx.x >> 7, tile = blockIdx.x & 127;      // 8 x-tiles x 16 y-tiles
    int tx0 = (tile & 7) << 4, ty0 = (tile >> 3) << 3;     // 16 wide x 8 tall
    int s = threadIdx.x >> 7, px = threadIdx.x & 127;
    int lx = px & 15, ly = px >> 4;                        // 16 x 8
    int w = tx0 + lx, h = ty0 + ly;

    int nb = cnt[b];
    int lo = (nb * s) >> 3, hi = (nb * (s + 1)) >> 3;

    float fw = (float)w, fh = (float)h;
    float a0 = 0.f, a1 = 0.f, a2 = 0.f;
    for (int q = lo; q < hi; ++q) {
        int n = cidx[b * NBOX + q];
        int rc = rect[b * NBOX + n];
        int wlo = rc & 255, whi = (rc >> 8) & 255;
        int hlo = (rc >> 16) & 255, hhi = (rc >> 24) & 255;
        if (whi < tx0 || wlo > tx0 + 15 || hhi < ty0 || hlo > ty0 + 7) continue;
        int g = b * NBOX + n;
        float wg = wgt[g];
        float pxx = fmaf(fw, sxs[g], oxs[g]);
        float pyy = fmaf(fh, sys[g], oys[g]);
        float x0 = floorf(pxx), y0 = floorf(pyy);
        if (x0 < -1.0f || x0 > 63.0f || y0 < -1.0f || y0 > 63.0f) continue;
        float wx = pxx - x0, wy = pyy - y0;
        int ix = (int)x0, iy = (int)y0;
        int x0c = max(ix, 0), x1c = min(ix + 1, 63);
        int y0c = max(iy, 0), y1c = min(iy + 1, 63);
        float m00 = (ix >= 0 && iy >= 0) ? 1.f : 0.f;
        float m01 = (ix + 1 <= 63 && iy >= 0) ? 1.f : 0.f;
        float m10 = (ix >= 0 && iy + 1 <= 63) ? 1.f : 0.f;
        float m11 = (ix + 1 <= 63 && iy + 1 <= 63) ? 1.f : 0.f;
        float w00 = (1.f - wy) * (1.f - wx) * m00;
        float w01 = (1.f - wy) * wx * m01;
        float w10 = wy * (1.f - wx) * m10;
        float w11 = wy * wx * m11;
        const float* img = dec + (size_t)binst[g] * 12288;   // (64,64,3) HWC
        int b00 = (y0c * 64 + x0c) * 3, b01 = (y0c * 64 + x1c) * 3;
        int b10 = (y1c * 64 + x0c) * 3, b11 = (y1c * 64 + x1c) * 3;
        a0 += wg * (w00 * img[b00]   + w01 * img[b01]   + w10 * img[b10]   + w11 * img[b11]);
        a1 += wg * (w00 * img[b00+1] + w01 * img[b01+1] + w10 * img[b10+1] + w11 * img[b11+1]);
        a2 += wg * (w00 * img[b00+2] + w01 * img[b01+2] + w10 * img[b10+2] + w11 * img[b11+2]);
    }
    pls[s][px][0] = a0; pls[s][px][1] = a1; pls[s][px][2] = a2;
    __syncthreads();

    if (threadIdx.x < 384) {
        int c = threadIdx.x >> 7, p2 = threadIdx.x & 127;
        float v = 0.f;
        #pragma unroll
        for (int t = 0; t < 8; ++t) v += pls[t][p2][c];
        int h2 = ty0 + (p2 >> 4), w2 = tx0 + (p2 & 15);
        out[((b * 3 + c) * 128 + h2) * 128 + w2] = v;
    }
}

extern "C" void kernel_launch(void* const* d_in, const int* in_sizes, int n_in,
                              void* d_out, int out_size, void* d_ws, size_t ws_size,
                              hipStream_t stream)
{
    const float* z_what    = (const float*)d_in[0];   // (4,85,64)
    const float* z_where   = (const float*)d_in[1];   // (4,380,4)
    const int*   z_present = (const int*)  d_in[2];   // (4,380,1)
    const float* z_depth   = (const float*)d_in[3];   // (4,85,1)

    // workspace: dec 16.71 MB | params ~55 KB
    char* ws = (char*)d_ws;
    float* dec = (float*)ws;                           // 340*12288 f32
    float* P   = (float*)(ws + 16711680);
    float* wgt = P,        *sxs = P + 1520, *oxs = P + 2 * 1520;
    float* sys = P + 3 * 1520, *oys = P + 4 * 1520;
    int* binst = (int*)(P + 5 * 1520);
    int* rect  = binst + 1520;
    int* cidx  = binst + 2 * 1520;
    int* cnt   = binst + 3 * 1520;

    decode_fused_k<<<dim3(NINST + 4), dim3(512), 0, stream>>>(
        z_what,
        (const float*)d_in[4],  (const float*)d_in[5],
        (const float*)d_in[6],  (const float*)d_in[7],
        (const float*)d_in[8],  (const float*)d_in[9],
        (const float*)d_in[10], (const float*)d_in[11],
        (const float*)d_in[12], (const float*)d_in[13],
        (const float*)d_in[14], (const float*)d_in[15],
        z_where, z_present, z_depth,
        wgt, sxs, oxs, sys, oys, binst, rect, cidx, cnt,
        dec);

    composite_k<<<dim3(512), dim3(1024), 0, stream>>>(
        dec, wgt, sxs, oxs, sys, oys, binst, rect, cidx, cnt, (float*)d_out);
}